// Round 5
// baseline (468.901 us; speedup 1.0000x reference)
//
#include <hip/hip_runtime.h>

// TurboQuant round-trip, numpy-fp32-replicating quant path (PASSING config —
// do not change rounding here):
//  - norm: x*x separately rounded (contract off), numpy pairwise-8 scalar sum,
//    IEEE sqrt via fp64.
//  - xs = x / scale: IEEE RN fp32 division (native f32 div sequence, no
//    fast-math => correctly rounded, same bits as fp64-div-then-round except
//    ~2^-29 double-rounding cases).
//  - z_j = <xs, R[j,:]>: sequential-k single-chain fmaf.
//  - argmin |z - cb[i]| fp32, strict <, first-index ties — tracked by VALUE
//    (cndmask), no runtime-indexed array (avoids scratch).
// Perf structure: phase-split so register pressure never exceeds ~last phase:
//   P1: xs (64 regs).  P2: 64 fully-unrolled z/argmin -> zh[64] (static idx).
//   P3: recon in 4 k-chunks of 16 acc regs; per-k j-order unchanged (0..63)
//   so recon bits match the fused version.

#define TQ_D 64
#define TQ_NLEV 16

__global__ __launch_bounds__(256) void tq_f32(
    const float* __restrict__ x,
    const float* __restrict__ cbk,
    const float* __restrict__ R,
    float* __restrict__ out,
    int nrows)
{
#pragma clang fp contract(off)
    int row = blockIdx.x * blockDim.x + threadIdx.x;
    if (row >= nrows) return;

    const float* xr = x + (size_t)row * TQ_D;

    // ---- P1: load row ----
    float xs[TQ_D];
#pragma unroll
    for (int k = 0; k < TQ_D; k += 4) {
        float4 v = *reinterpret_cast<const float4*>(xr + k);
        xs[k] = v.x; xs[k + 1] = v.y; xs[k + 2] = v.z; xs[k + 3] = v.w;
    }

    // numpy pairwise-8 (scalar path, n=64) sum of squares — DO NOT REORDER
    float r8[8];
#pragma unroll
    for (int j = 0; j < 8; ++j) r8[j] = xs[j] * xs[j];
#pragma unroll
    for (int i = 8; i < TQ_D; i += 8) {
#pragma unroll
        for (int j = 0; j < 8; ++j) {
            float t = xs[i + j] * xs[i + j];   // separate rounding (no fma)
            r8[j] = r8[j] + t;
        }
    }
    float ss = ((r8[0] + r8[1]) + (r8[2] + r8[3])) + ((r8[4] + r8[5]) + (r8[6] + r8[7]));

    float scale = (float)sqrt((double)ss);     // IEEE fp32 sqrt result
    scale = fmaxf(scale, 1e-8f);               // np.clip(norm, 1e-8, None)

#pragma unroll
    for (int k = 0; k < TQ_D; ++k)
        xs[k] = xs[k] / scale;                 // IEEE RN fp32 division

    float cb[TQ_NLEV];
#pragma unroll
    for (int i = 0; i < TQ_NLEV; ++i) cb[i] = cbk[i];

    // ---- P2: all 64 z_j -> zh[j], fully unrolled (static zh indexing) ----
    float zh[TQ_D];
#pragma unroll
    for (int j = 0; j < TQ_D; ++j) {
        const float* rj = R + j * TQ_D;        // uniform + const j -> s_loads

        float z = 0.0f;
#pragma unroll
        for (int k = 0; k < TQ_D; ++k)         // sequential chain — DO NOT REORDER
            z = fmaf(xs[k], rj[k], z);

        float best = fabsf(z - cb[0]);
        float v = cb[0];
#pragma unroll
        for (int i = 1; i < TQ_NLEV; ++i) {
            float d = fabsf(z - cb[i]);
            bool c = d < best;                  // strict <, first index wins
            best = c ? d : best;
            v = c ? cb[i] : v;
        }
        zh[j] = v;
    }

    // ---- P3: recon in 4 chunks of 16 k's; j ascending per k (order kept) ----
    float* orow = out + (size_t)row * TQ_D;
#pragma unroll
    for (int c = 0; c < 4; ++c) {
        float acc[16];
#pragma unroll
        for (int k = 0; k < 16; ++k) acc[k] = 0.0f;
#pragma unroll
        for (int j = 0; j < TQ_D; ++j) {
            const float* rj = R + j * TQ_D + c * 16;
            float zhj = zh[j];
#pragma unroll
            for (int k = 0; k < 16; ++k)
                acc[k] = fmaf(zhj, rj[k], acc[k]);
        }
#pragma unroll
        for (int k = 0; k < 16; k += 4) {
            float4 v;
            v.x = acc[k]     * scale;
            v.y = acc[k + 1] * scale;
            v.z = acc[k + 2] * scale;
            v.w = acc[k + 3] * scale;
            *reinterpret_cast<float4*>(orow + c * 16 + k) = v;
        }
    }
}

extern "C" void kernel_launch(void* const* d_in, const int* in_sizes, int n_in,
                              void* d_out, int out_size, void* d_ws, size_t ws_size,
                              hipStream_t stream) {
    const float* x   = (const float*)d_in[0];
    const float* cbk = (const float*)d_in[1];
    const float* R   = (const float*)d_in[2];
    float* out = (float*)d_out;

    const int nrows = in_sizes[0] / TQ_D;      // 262144
    const int blocks = (nrows + 255) / 256;

    tq_f32<<<blocks, 256, 0, stream>>>(x, cbk, R, out, nrows);
}

// Round 6
// 301.326 us; speedup vs baseline: 1.5561x; 1.5561x over previous
//
#include <hip/hip_runtime.h>

// TurboQuant round-trip, numpy-fp32-replicating quant path (PASSING bits —
// do not change any rounding/order here):
//  - norm: x*x separately rounded (contract off), numpy pairwise-8 scalar sum,
//    IEEE sqrt via fp64 then cast.
//  - xs = x / scale: IEEE RN fp32 division (validated bit-compatible in r5).
//  - z_j = <xs, R[j,:]>: sequential-k single-chain fmaf.
//  - argmin |z - cb[i]| fp32, strict <, first-index ties, tracked by value.
//  - recon fused per-j into acc[64] (same order as the passing round-4 run).
//
// Perf fix vs round 4/5: the live set (xs[64]+acc[64]+cb[16]+temps ~190 f32)
// was being spilled to scratch under the default occupancy-targeting VGPR cap
// (r4: 72 VGPR / VALUBusy 46%; r5: 132 VGPR / 250MB spill writes).
// __launch_bounds__(256, 2) => 2 blocks/CU (2 waves/SIMD), VGPR cap 256:
// everything fits in registers, zero scratch.

#define TQ_D 64
#define TQ_NLEV 16

__global__ __launch_bounds__(256, 2) void tq_f32(
    const float* __restrict__ x,
    const float* __restrict__ cbk,
    const float* __restrict__ R,
    float* __restrict__ out,
    int nrows)
{
#pragma clang fp contract(off)
    int row = blockIdx.x * blockDim.x + threadIdx.x;
    if (row >= nrows) return;

    const float* xr = x + (size_t)row * TQ_D;

    float xs[TQ_D];
#pragma unroll
    for (int k = 0; k < TQ_D; k += 4) {
        float4 v = *reinterpret_cast<const float4*>(xr + k);
        xs[k] = v.x; xs[k + 1] = v.y; xs[k + 2] = v.z; xs[k + 3] = v.w;
    }

    // ---- numpy pairwise-8 (scalar path, n=64) sum of squares — DO NOT REORDER
    float r8[8];
#pragma unroll
    for (int j = 0; j < 8; ++j) r8[j] = xs[j] * xs[j];
#pragma unroll
    for (int i = 8; i < TQ_D; i += 8) {
#pragma unroll
        for (int j = 0; j < 8; ++j) {
            float t = xs[i + j] * xs[i + j];   // separate rounding (no fma)
            r8[j] = r8[j] + t;
        }
    }
    float ss = ((r8[0] + r8[1]) + (r8[2] + r8[3])) + ((r8[4] + r8[5]) + (r8[6] + r8[7]));

    float scale = (float)sqrt((double)ss);     // IEEE fp32 sqrt result
    scale = fmaxf(scale, 1e-8f);               // np.clip(norm, 1e-8, None)

#pragma unroll
    for (int k = 0; k < TQ_D; ++k)
        xs[k] = xs[k] / scale;                 // IEEE RN fp32 division

    float cb[TQ_NLEV];
#pragma unroll
    for (int i = 0; i < TQ_NLEV; ++i) cb[i] = cbk[i];

    float acc[TQ_D];
#pragma unroll
    for (int k = 0; k < TQ_D; ++k) acc[k] = 0.0f;

    // ---- fused: z_j (f32 chain) -> argmin -> acc += zh_j * R[j,:] ----
#pragma unroll 2
    for (int j = 0; j < TQ_D; ++j) {
        const float* rj = R + j * TQ_D;        // wave-uniform -> s_loads

        float z = 0.0f;
#pragma unroll
        for (int k = 0; k < TQ_D; ++k)         // sequential chain — DO NOT REORDER
            z = fmaf(xs[k], rj[k], z);

        float best = fabsf(z - cb[0]);
        float zh = cb[0];
#pragma unroll
        for (int i = 1; i < TQ_NLEV; ++i) {
            float d = fabsf(z - cb[i]);
            bool c = d < best;                  // strict <, first index wins
            best = c ? d : best;
            zh = c ? cb[i] : zh;
        }

#pragma unroll
        for (int k = 0; k < TQ_D; ++k)
            acc[k] = fmaf(zh, rj[k], acc[k]);
    }

    float* orow = out + (size_t)row * TQ_D;
#pragma unroll
    for (int k = 0; k < TQ_D; k += 4) {
        float4 v;
        v.x = acc[k]     * scale;
        v.y = acc[k + 1] * scale;
        v.z = acc[k + 2] * scale;
        v.w = acc[k + 3] * scale;
        *reinterpret_cast<float4*>(orow + k) = v;
    }
}

extern "C" void kernel_launch(void* const* d_in, const int* in_sizes, int n_in,
                              void* d_out, int out_size, void* d_ws, size_t ws_size,
                              hipStream_t stream) {
    const float* x   = (const float*)d_in[0];
    const float* cbk = (const float*)d_in[1];
    const float* R   = (const float*)d_in[2];
    float* out = (float*)d_out;

    const int nrows = in_sizes[0] / TQ_D;      // 262144
    const int blocks = (nrows + 255) / 256;

    tq_f32<<<blocks, 256, 0, stream>>>(x, cbk, R, out, nrows);
}

// Round 8
// 276.079 us; speedup vs baseline: 1.6984x; 1.0914x over previous
//
#include <hip/hip_runtime.h>

// TurboQuant round-trip, numpy-fp32-replicating quant path (PASSING bits from
// round 4 — no rounding/order changes on the quant side).
//
// Perf structure (round 7): two-kernel split so no kernel ever holds two
// 64-float arrays live (r4/r6's fused kernel held xs[64]+acc[64] ~200 regs ->
// AGPR shuffling, 2 waves/SIMD, VALUBusy 44%).
//   K1 tq_quant: xs[64]-resident; z-chain + argmin; writes zh values via a
//      rolling float4 (no acc array). ~90 live regs.
//   K2 tq_recon: acc[64]-resident; reads zh as float4 quads (static component
//      extraction); same ascending-j fmaf accumulation as round 4 -> output
//      bit-identical. ~70 live regs.
// Fallback: fused round-6 kernel if ws_size can't hold zh+scale (68.2 MB).

#define TQ_D 64
#define TQ_NLEV 16

// ---------------- K1: quantize ----------------
__global__ __launch_bounds__(256) void tq_quant(
    const float* __restrict__ x,
    const float* __restrict__ cbk,
    const float* __restrict__ R,
    float* __restrict__ zh_ws,      // [nrows*64]
    float* __restrict__ scale_ws,   // [nrows]
    int nrows)
{
#pragma clang fp contract(off)
    int row = blockIdx.x * blockDim.x + threadIdx.x;
    if (row >= nrows) return;

    const float* xr = x + (size_t)row * TQ_D;

    float xs[TQ_D];
#pragma unroll
    for (int k = 0; k < TQ_D; k += 4) {
        float4 v = *reinterpret_cast<const float4*>(xr + k);
        xs[k] = v.x; xs[k + 1] = v.y; xs[k + 2] = v.z; xs[k + 3] = v.w;
    }

    // numpy pairwise-8 (scalar path, n=64) sum of squares — DO NOT REORDER
    float r8[8];
#pragma unroll
    for (int j = 0; j < 8; ++j) r8[j] = xs[j] * xs[j];
#pragma unroll
    for (int i = 8; i < TQ_D; i += 8) {
#pragma unroll
        for (int j = 0; j < 8; ++j) {
            float t = xs[i + j] * xs[i + j];   // separate rounding (no fma)
            r8[j] = r8[j] + t;
        }
    }
    float ss = ((r8[0] + r8[1]) + (r8[2] + r8[3])) + ((r8[4] + r8[5]) + (r8[6] + r8[7]));

    float scale = (float)sqrt((double)ss);     // IEEE fp32 sqrt result
    scale = fmaxf(scale, 1e-8f);               // np.clip(norm, 1e-8, None)

#pragma unroll
    for (int k = 0; k < TQ_D; ++k)
        xs[k] = xs[k] / scale;                 // IEEE RN fp32 division

    float cb[TQ_NLEV];
#pragma unroll
    for (int i = 0; i < TQ_NLEV; ++i) cb[i] = cbk[i];

    float* zrow = zh_ws + (size_t)row * TQ_D;
    for (int jq = 0; jq < TQ_D / 4; ++jq) {    // 16 iterations, rolling float4
        float4 w;
#pragma unroll
        for (int t = 0; t < 4; ++t) {
            const float* rj = R + (jq * 4 + t) * TQ_D;   // wave-uniform -> s_loads

            float z = 0.0f;
#pragma unroll
            for (int k = 0; k < TQ_D; ++k)     // sequential chain — DO NOT REORDER
                z = fmaf(xs[k], rj[k], z);

            float best = fabsf(z - cb[0]);
            float zh = cb[0];
#pragma unroll
            for (int i = 1; i < TQ_NLEV; ++i) {
                float d = fabsf(z - cb[i]);
                bool c = d < best;              // strict <, first index wins
                best = c ? d : best;
                zh = c ? cb[i] : zh;
            }
            if      (t == 0) w.x = zh;
            else if (t == 1) w.y = zh;
            else if (t == 2) w.z = zh;
            else             w.w = zh;
        }
        *reinterpret_cast<float4*>(zrow + jq * 4) = w;
    }
    scale_ws[row] = scale;
}

// ---------------- K2: reconstruct ----------------
__global__ __launch_bounds__(256) void tq_recon(
    const float* __restrict__ zh_ws,
    const float* __restrict__ scale_ws,
    const float* __restrict__ R,
    float* __restrict__ out,
    int nrows)
{
#pragma clang fp contract(off)
    int row = blockIdx.x * blockDim.x + threadIdx.x;
    if (row >= nrows) return;

    const float* zrow = zh_ws + (size_t)row * TQ_D;
    float scale = scale_ws[row];

    float acc[TQ_D];
#pragma unroll
    for (int k = 0; k < TQ_D; ++k) acc[k] = 0.0f;

#pragma unroll 2
    for (int jq = 0; jq < TQ_D / 4; ++jq) {
        float4 zq = *reinterpret_cast<const float4*>(zrow + jq * 4);
#pragma unroll
        for (int t = 0; t < 4; ++t) {
            float zh = (t == 0) ? zq.x : (t == 1) ? zq.y : (t == 2) ? zq.z : zq.w;
            const float* rj = R + (jq * 4 + t) * TQ_D;   // wave-uniform -> s_loads
#pragma unroll
            for (int k = 0; k < TQ_D; ++k)     // same ascending-j order as r4
                acc[k] = fmaf(zh, rj[k], acc[k]);
        }
    }

    float* orow = out + (size_t)row * TQ_D;
#pragma unroll
    for (int k = 0; k < TQ_D; k += 4) {
        float4 v;
        v.x = acc[k]     * scale;
        v.y = acc[k + 1] * scale;
        v.z = acc[k + 2] * scale;
        v.w = acc[k + 3] * scale;
        *reinterpret_cast<float4*>(orow + k) = v;
    }
}

// ---------------- Fallback: fused (round-6, passing) ----------------
__global__ __launch_bounds__(256) void tq_fused(
    const float* __restrict__ x,
    const float* __restrict__ cbk,
    const float* __restrict__ R,
    float* __restrict__ out,
    int nrows)
{
#pragma clang fp contract(off)
    int row = blockIdx.x * blockDim.x + threadIdx.x;
    if (row >= nrows) return;

    const float* xr = x + (size_t)row * TQ_D;

    float xs[TQ_D];
#pragma unroll
    for (int k = 0; k < TQ_D; k += 4) {
        float4 v = *reinterpret_cast<const float4*>(xr + k);
        xs[k] = v.x; xs[k + 1] = v.y; xs[k + 2] = v.z; xs[k + 3] = v.w;
    }
    float r8[8];
#pragma unroll
    for (int j = 0; j < 8; ++j) r8[j] = xs[j] * xs[j];
#pragma unroll
    for (int i = 8; i < TQ_D; i += 8) {
#pragma unroll
        for (int j = 0; j < 8; ++j) {
            float t = xs[i + j] * xs[i + j];
            r8[j] = r8[j] + t;
        }
    }
    float ss = ((r8[0] + r8[1]) + (r8[2] + r8[3])) + ((r8[4] + r8[5]) + (r8[6] + r8[7]));
    float scale = (float)sqrt((double)ss);
    scale = fmaxf(scale, 1e-8f);
#pragma unroll
    for (int k = 0; k < TQ_D; ++k) xs[k] = xs[k] / scale;

    float cb[TQ_NLEV];
#pragma unroll
    for (int i = 0; i < TQ_NLEV; ++i) cb[i] = cbk[i];

    float acc[TQ_D];
#pragma unroll
    for (int k = 0; k < TQ_D; ++k) acc[k] = 0.0f;

#pragma unroll 2
    for (int j = 0; j < TQ_D; ++j) {
        const float* rj = R + j * TQ_D;
        float z = 0.0f;
#pragma unroll
        for (int k = 0; k < TQ_D; ++k) z = fmaf(xs[k], rj[k], z);
        float best = fabsf(z - cb[0]);
        float zh = cb[0];
#pragma unroll
        for (int i = 1; i < TQ_NLEV; ++i) {
            float d = fabsf(z - cb[i]);
            bool c = d < best;
            best = c ? d : best;
            zh = c ? cb[i] : zh;
        }
#pragma unroll
        for (int k = 0; k < TQ_D; ++k) acc[k] = fmaf(zh, rj[k], acc[k]);
    }

    float* orow = out + (size_t)row * TQ_D;
#pragma unroll
    for (int k = 0; k < TQ_D; k += 4) {
        float4 v;
        v.x = acc[k]     * scale;
        v.y = acc[k + 1] * scale;
        v.z = acc[k + 2] * scale;
        v.w = acc[k + 3] * scale;
        *reinterpret_cast<float4*>(orow + k) = v;
    }
}

extern "C" void kernel_launch(void* const* d_in, const int* in_sizes, int n_in,
                              void* d_out, int out_size, void* d_ws, size_t ws_size,
                              hipStream_t stream) {
    const float* x   = (const float*)d_in[0];
    const float* cbk = (const float*)d_in[1];
    const float* R   = (const float*)d_in[2];
    float* out = (float*)d_out;

    const int nrows = in_sizes[0] / TQ_D;      // 262144
    const int blocks = (nrows + 255) / 256;

    const size_t need = (size_t)nrows * TQ_D * sizeof(float)   // zh
                      + (size_t)nrows * sizeof(float);         // scale

    if (ws_size >= need) {
        float* scale_ws = (float*)d_ws;                        // [nrows]
        float* zh_ws    = scale_ws + nrows;                    // [nrows*64], 16B-aligned
        tq_quant<<<blocks, 256, 0, stream>>>(x, cbk, R, zh_ws, scale_ws, nrows);
        tq_recon<<<blocks, 256, 0, stream>>>(zh_ws, scale_ws, R, out, nrows);
    } else {
        tq_fused<<<blocks, 256, 0, stream>>>(x, cbk, R, out, nrows);
    }
}